// Round 4
// baseline (400.846 us; speedup 1.0000x reference)
//
#include <hip/hip_runtime.h>
#include <hip/hip_bf16.h>
#include <stdint.h>

// Problem constants
#define DM   1024   // d_model = d_enc
#define DKV  64     // d_k = d_v
#define NH   16
#define NB   8
#define SLEN 1024   // LQ = LK

typedef float  f32x4  __attribute__((ext_vector_type(4)));
typedef __bf16 bf16x8 __attribute__((ext_vector_type(8)));

#define L2E 1.44269504089f

__device__ __forceinline__ void gload_lds16(const void* g, void* l) {
  __builtin_amdgcn_global_load_lds(
      (const __attribute__((address_space(1))) void*)g,
      (__attribute__((address_space(3))) void*)l, 16, 0, 0);
}

__device__ __forceinline__ unsigned short f2bf(float f) {  // RNE fp32->bf16
  uint32_t u = __builtin_bit_cast(uint32_t, f);
  u += 0x7fffu + ((u >> 16) & 1u);
  return (unsigned short)(u >> 16);
}

// ------------- weight transpose+convert: W[h][d][k] -> WT[h][k][d] bf16 -------------
// grid (16 d-chunks, 16 heads, 3 weights), block 256
__global__ void k_wT(const float* __restrict__ Wq, const float* __restrict__ Wk,
                     const float* __restrict__ Wv, unsigned short* __restrict__ Tq,
                     unsigned short* __restrict__ Tk, unsigned short* __restrict__ Tv) {
  __shared__ float tile[64][65];
  const int t = threadIdx.x;
  const int dc = blockIdx.x, h = blockIdx.y, s = blockIdx.z;
  const float* W = (s == 0) ? Wq : (s == 1) ? Wk : Wv;
  unsigned short* T = (s == 0) ? Tq : (s == 1) ? Tk : Tv;
#pragma unroll
  for (int i = 0; i < 4; ++i) {
    int idx = i * 256 + t;
    int d = idx >> 4, kg = idx & 15;
    float4 v = *(const float4*)(W + ((size_t)h * DM + dc * 64 + d) * DKV + kg * 4);
    tile[d][kg * 4 + 0] = v.x; tile[d][kg * 4 + 1] = v.y;
    tile[d][kg * 4 + 2] = v.z; tile[d][kg * 4 + 3] = v.w;
  }
  __syncthreads();
  int k = t >> 2, dg = t & 3;
  union { unsigned short u[8]; int4 v; } o0, o1;
#pragma unroll
  for (int j = 0; j < 8; ++j) o0.u[j] = f2bf(tile[dg * 16 + j][k]);
#pragma unroll
  for (int j = 0; j < 8; ++j) o1.u[j] = f2bf(tile[dg * 16 + 8 + j][k]);
  unsigned short* dst = T + ((size_t)h * DKV + k) * DM + dc * 64 + dg * 16;
  *(int4*)dst = o0.v;
  *(int4*)(dst + 8) = o1.v;
}

// ---------------- mask -> packed bits (bit=1 means VALID) ----------------
__global__ void k_pack(const int* __restrict__ m, uint32_t* __restrict__ out) {
  int wi = blockIdx.x * 256 + threadIdx.x;       // word index, 32 s-positions each
  const int* p = m + (size_t)wi * 32;
  uint32_t bits = 0;
#pragma unroll
  for (int i = 0; i < 8; ++i) {
    int4 v = *(const int4*)(p + i * 4);
    bits |= ((uint32_t)(v.x != 0)) << (i * 4 + 0);
    bits |= ((uint32_t)(v.y != 0)) << (i * 4 + 1);
    bits |= ((uint32_t)(v.z != 0)) << (i * 4 + 2);
    bits |= ((uint32_t)(v.w != 0)) << (i * 4 + 3);
  }
  out[wi] = bits;
}

// ---- GEMM: C = A_fp32[8192x1024] @ BT_bf16[1024x1024]^T + bias (A converted on the fly) ----
// EPI 0: C bf16 [8192][1024] (row, n) ; EPI 1: C bf16 VT[b][h][v][s]
// 128x128 tile, BK=32, 4 waves 2x2. A: reg-staged fp32->bf16 + swizzled ds_write.
// B: global_load_lds w/ source-pre-swizzled XOR (rule #21: linear dest).
template <int EPI>
__global__ __launch_bounds__(256, 2)
void k_gemmF(const float* __restrict__ A, const unsigned short* __restrict__ BT,
             const float* __restrict__ bias, unsigned short* __restrict__ C) {
  __shared__ char As[8192];   // [128][32] bf16, pos p holds source slot p^(row&3)
  __shared__ char Bs[8192];
  const int t = threadIdx.x;
  const int w = t >> 6, lane = t & 63;
  const int g = lane >> 4, r16 = lane & 15;
  const int wm = w >> 1, wn = w & 1;
  const int m0 = blockIdx.y * 128, n0 = blockIdx.x * 128;
  const int arow = t >> 2, ac = t & 3;   // staging coords: row (+0/+64), 8-elem slot

  f32x4 acc[4][4] = {};
  for (int kt = 0; kt < DM / 32; ++kt) {
    // A fp32 -> registers (global reads, no LDS touch; issued before barrier)
    float4 a0[2], a1[2];
#pragma unroll
    for (int i = 0; i < 2; ++i) {
      const float* src = A + (size_t)(m0 + arow + i * 64) * DM + kt * 32 + ac * 8;
      a0[i] = *(const float4*)src;
      a1[i] = *(const float4*)(src + 4);
    }
    __syncthreads();                       // prior-iter LDS readers done
#pragma unroll
    for (int i = 0; i < 2; ++i) {
      int row = arow + i * 64;
      int pos = ac ^ (row & 3);
      // B: 64 rows per call, linear LDS dest + inverse-swizzled source
      gload_lds16(BT + (size_t)(n0 + row) * DM + kt * 32 + pos * 8,
                  Bs + i * 4096 + w * 1024);
      // A: convert + swizzled ds_write_b128
      union { unsigned short u[8]; int4 v; } o;
      o.u[0] = f2bf(a0[i].x); o.u[1] = f2bf(a0[i].y);
      o.u[2] = f2bf(a0[i].z); o.u[3] = f2bf(a0[i].w);
      o.u[4] = f2bf(a1[i].x); o.u[5] = f2bf(a1[i].y);
      o.u[6] = f2bf(a1[i].z); o.u[7] = f2bf(a1[i].w);
      *(int4*)(As + row * 64 + (pos << 4)) = o.v;
    }
    __syncthreads();                       // drains vmcnt + lgkmcnt
    bf16x8 af[4], bfr[4];
#pragma unroll
    for (int m = 0; m < 4; ++m) {
      int row = wm * 64 + m * 16 + r16;
      af[m] = *(const bf16x8*)(As + row * 64 + ((g ^ (row & 3)) << 4));
    }
#pragma unroll
    for (int n = 0; n < 4; ++n) {
      int row = wn * 64 + n * 16 + r16;
      bfr[n] = *(const bf16x8*)(Bs + row * 64 + ((g ^ (row & 3)) << 4));
    }
#pragma unroll
    for (int m = 0; m < 4; ++m)
#pragma unroll
      for (int n = 0; n < 4; ++n)
        acc[m][n] = __builtin_amdgcn_mfma_f32_16x16x32_bf16(af[m], bfr[n], acc[m][n], 0, 0, 0);
  }
#pragma unroll
  for (int m = 0; m < 4; ++m) {
    int rowb = m0 + wm * 64 + m * 16 + 4 * g;     // 4 consecutive rows rowb..rowb+3
#pragma unroll
    for (int n = 0; n < 4; ++n) {
      int col = n0 + wn * 64 + n * 16 + r16;
      float bv = bias[col];
      if (EPI == 0) {
#pragma unroll
        for (int r = 0; r < 4; ++r)
          C[(size_t)(rowb + r) * DM + col] = f2bf(acc[m][n][r] + bv);
      } else {
        int b = rowb >> 10, s = rowb & 1023;
        int h = col >> 6, v = col & 63;
        union { unsigned short u[4]; ushort4 q; } o;
#pragma unroll
        for (int r = 0; r < 4; ++r) o.u[r] = f2bf(acc[m][n][r] + bv);
        *(ushort4*)(C + (((size_t)(b * NH + h) * DKV + v) << 10) + s) = o.q;
      }
    }
  }
}

// ---------------- fused masked attention ----------------
// grid (16 q-tiles, B*H). block 256 = 4 waves; wave owns 16 q-rows.
// s-tiles of 64: stage K[64][64], VT[64][64] via swizzled global_load_lds;
// online softmax; P transposed through per-wave swizzled LDS.
__global__ __launch_bounds__(256, 2)
void k_attn(const unsigned short* __restrict__ Q, const unsigned short* __restrict__ K,
            const unsigned short* __restrict__ VT, const uint32_t* __restrict__ MP,
            float* __restrict__ O) {
  __shared__ char Ks[8192];   // [64][64] bf16, slot^=(row&7)
  __shared__ char Vs[8192];   // [64 v][64 s] bf16, slot^=(row&7)
  __shared__ char Ps[8192];   // per-wave [16][64] bf16, slot^=(row&7)
  const int t = threadIdx.x, w = t >> 6, lane = t & 63;
  const int g = lane >> 4, r16 = lane & 15;
  const int qt = blockIdx.x, bh = blockIdx.y;
  const int b = bh >> 4, h = bh & 15;
  const int q0 = qt * 64 + w * 16;                 // wave's q base (within b)

  bf16x8 aq[2];
#pragma unroll
  for (int kc = 0; kc < 2; ++kc)
    aq[kc] = *(const bf16x8*)(Q + (size_t)(b * SLEN + q0 + r16) * DM + h * DKV + kc * 32 + g * 8);

  f32x4 oacc[4] = {};
  float mrun[4], lrun[4], anyv[4];
#pragma unroll
  for (int r = 0; r < 4; ++r) { mrun[r] = -1e30f; lrun[r] = 0.f; anyv[r] = 0.f; }

  const unsigned short* Kbase = K  + (size_t)b * SLEN * DM + h * DKV;
  const unsigned short* Vbase = VT + (size_t)bh * DKV * SLEN;
  const uint32_t*       Mbase = MP + (size_t)(b * SLEN + q0) * 32;

  for (int st = 0; st < 16; ++st) {
    const int s0 = st * 64;
    __syncthreads();
#pragma unroll
    for (int i = 0; i < 2; ++i) {          // 32 rows per call
      int row  = (t >> 3) + i * 32;
      int slot = (t & 7) ^ (row & 7);
      gload_lds16(Kbase + (size_t)(s0 + row) * DM + slot * 8, Ks + i * 4096 + w * 1024);
      gload_lds16(Vbase + (size_t)row * SLEN + s0 + slot * 8, Vs + i * 4096 + w * 1024);
    }
    __syncthreads();

    // S = Q K^T  (rows q, cols s)
    f32x4 sacc[4];
#pragma unroll
    for (int f = 0; f < 4; ++f) {
      sacc[f] = (f32x4){0.f, 0.f, 0.f, 0.f};
#pragma unroll
      for (int kc = 0; kc < 2; ++kc) {
        int row = f * 16 + r16;
        int sl  = kc * 4 + g;
        bf16x8 bk_ = *(const bf16x8*)(Ks + row * 128 + ((sl ^ (row & 7)) << 4));
        sacc[f] = __builtin_amdgcn_mfma_f32_16x16x32_bf16(aq[kc], bk_, sacc[f], 0, 0, 0);
      }
    }

    // mask + online softmax (rows 4g+r, cols f*16+r16)
    uint32_t mw[4][2];
#pragma unroll
    for (int r = 0; r < 4; ++r)
#pragma unroll
      for (int fw = 0; fw < 2; ++fw)
        mw[r][fw] = Mbase[(size_t)(4 * g + r) * 32 + (s0 >> 5) + fw];

    float pv[4][4], mt[4];
#pragma unroll
    for (int r = 0; r < 4; ++r) mt[r] = -1e30f;
#pragma unroll
    for (int f = 0; f < 4; ++f) {
      uint32_t bit = 1u << (((f & 1) << 4) | r16);
#pragma unroll
      for (int r = 0; r < 4; ++r) {
        bool valid = (mw[r][f >> 1] & bit) != 0;
        float v = valid ? sacc[f][r] * 0.125f : -1e30f;
        pv[f][r] = v;
        mt[r] = fmaxf(mt[r], v);
      }
    }
#pragma unroll
    for (int d = 1; d < 16; d <<= 1)
#pragma unroll
      for (int r = 0; r < 4; ++r) mt[r] = fmaxf(mt[r], __shfl_xor(mt[r], d));

    float mnew[4], corr[4], lt[4];
#pragma unroll
    for (int r = 0; r < 4; ++r) {
      anyv[r] = fmaxf(anyv[r], (mt[r] > -5e29f) ? 1.f : 0.f);
      mnew[r] = fmaxf(mrun[r], mt[r]);
      corr[r] = exp2f((mrun[r] - mnew[r]) * L2E);
      lt[r] = 0.f;
    }
#pragma unroll
    for (int f = 0; f < 4; ++f)
#pragma unroll
      for (int r = 0; r < 4; ++r) {
        float p = exp2f((pv[f][r] - mnew[r]) * L2E);
        pv[f][r] = p;
        lt[r] += p;
      }
#pragma unroll
    for (int d = 1; d < 16; d <<= 1)
#pragma unroll
      for (int r = 0; r < 4; ++r) lt[r] += __shfl_xor(lt[r], d);
#pragma unroll
    for (int r = 0; r < 4; ++r) {
      lrun[r] = lrun[r] * corr[r] + lt[r];
      mrun[r] = mnew[r];
    }
#pragma unroll
    for (int n = 0; n < 4; ++n)
#pragma unroll
      for (int r = 0; r < 4; ++r) oacc[n][r] *= corr[r];

    // P (D-layout) -> per-wave LDS (A-layout source), swizzled
#pragma unroll
    for (int f = 0; f < 4; ++f)
#pragma unroll
      for (int r = 0; r < 4; ++r) {
        int qr = 4 * g + r;
        int col = f * 16 + r16;
        int byteoff = qr * 128 + (((col >> 3) ^ (qr & 7)) << 4) + ((col & 7) << 1);
        *(unsigned short*)(Ps + w * 2048 + byteoff) = f2bf(pv[f][r]);
      }

    bf16x8 pa[2];
#pragma unroll
    for (int ks = 0; ks < 2; ++ks) {
      int sl = ks * 4 + g;
      pa[ks] = *(const bf16x8*)(Ps + w * 2048 + r16 * 128 + ((sl ^ (r16 & 7)) << 4));
    }
#pragma unroll
    for (int n = 0; n < 4; ++n)
#pragma unroll
      for (int ks = 0; ks < 2; ++ks) {
        int row = n * 16 + r16;
        int sl  = ks * 4 + g;
        bf16x8 bv_ = *(const bf16x8*)(Vs + row * 128 + ((sl ^ (row & 7)) << 4));
        oacc[n] = __builtin_amdgcn_mfma_f32_16x16x32_bf16(pa[ks], bv_, oacc[n], 0, 0, 0);
      }
  }

  float inv[4];
#pragma unroll
  for (int r = 0; r < 4; ++r) inv[r] = (anyv[r] > 0.f) ? (1.f / lrun[r]) : 0.f;
#pragma unroll
  for (int n = 0; n < 4; ++n)
#pragma unroll
    for (int r = 0; r < 4; ++r)
      O[(size_t)(b * SLEN + q0 + 4 * g + r) * (NH * DKV) + h * DKV + n * 16 + r16] =
          oacc[n][r] * inv[r];
}

extern "C" void kernel_launch(void* const* d_in, const int* in_sizes, int n_in,
                              void* d_out, int out_size, void* d_ws, size_t ws_size,
                              hipStream_t stream) {
  const float* dec = (const float*)d_in[0];
  const float* enc = (const float*)d_in[1];
  const int*   msk = (const int*)d_in[2];
  const float* Wq  = (const float*)d_in[3];
  const float* bq  = (const float*)d_in[4];
  const float* Wk  = (const float*)d_in[5];
  const float* bk  = (const float*)d_in[6];
  const float* Wv  = (const float*)d_in[7];
  const float* bv  = (const float*)d_in[8];
  float* out = (float*)d_out;

  // Compact 55 MB workspace layout (round-2 fix: the 87 MB layout likely
  // overran ws_size and corrupted the harness's pristine input copies —
  // first call passed, all post-restore calls deterministically off).
  char* ws = (char*)d_ws;
  const size_t MB = 1ull << 20;
  unsigned short* Tq = (unsigned short*)(ws + 0);        // [16][64][1024] bf16, 2 MB
  unsigned short* Tk = (unsigned short*)(ws + 2 * MB);
  unsigned short* Tv = (unsigned short*)(ws + 4 * MB);
  uint32_t*       MP = (uint32_t*)(ws + 6 * MB);         // [8192][32] bits, 1 MB
  unsigned short* Qb = (unsigned short*)(ws + 7 * MB);   // [8192][1024] bf16, 16 MB
  unsigned short* Kb = (unsigned short*)(ws + 23 * MB);  // 16 MB
  unsigned short* VT = (unsigned short*)(ws + 39 * MB);  // [128][64][1024] bf16, 16 MB

  k_wT<<<dim3(16, 16, 3), dim3(256), 0, stream>>>(Wq, Wk, Wv, Tq, Tk, Tv);
  k_pack<<<dim3(1024), dim3(256), 0, stream>>>(msk, MP);
  k_gemmF<0><<<dim3(8, 64), dim3(256), 0, stream>>>(dec, Tq, bq, Qb);
  k_gemmF<0><<<dim3(8, 64), dim3(256), 0, stream>>>(enc, Tk, bk, Kb);
  k_gemmF<1><<<dim3(8, 64), dim3(256), 0, stream>>>(enc, Tv, bv, VT);
  k_attn<<<dim3(16, 128), dim3(256), 0, stream>>>(Qb, Kb, VT, MP, out);
}

// Round 8
// 344.513 us; speedup vs baseline: 1.1635x; 1.1635x over previous
//
#include <hip/hip_runtime.h>
#include <hip/hip_bf16.h>
#include <stdint.h>

// Problem constants
#define DM   1024   // d_model = d_enc
#define DKV  64     // d_k = d_v
#define NH   16
#define NB   8
#define SLEN 1024   // LQ = LK

typedef float  f32x4  __attribute__((ext_vector_type(4)));
typedef __bf16 bf16x8 __attribute__((ext_vector_type(8)));

#define L2E 1.44269504089f

__device__ __forceinline__ void gload_lds16(const void* g, void* l) {
  __builtin_amdgcn_global_load_lds(
      (const __attribute__((address_space(1))) void*)g,
      (__attribute__((address_space(3))) void*)l, 16, 0, 0);
}

__device__ __forceinline__ unsigned short f2bf(float f) {  // RNE fp32->bf16
  uint32_t u = __builtin_bit_cast(uint32_t, f);
  u += 0x7fffu + ((u >> 16) & 1u);
  return (unsigned short)(u >> 16);
}

// ------------- weight transpose+convert: W[h][d][k] -> WT[h][k][d] bf16 -------------
// grid (16 d-chunks, 16 heads, 3 weights), block 256
__global__ void k_wT(const float* __restrict__ Wq, const float* __restrict__ Wk,
                     const float* __restrict__ Wv, unsigned short* __restrict__ Tq,
                     unsigned short* __restrict__ Tk, unsigned short* __restrict__ Tv) {
  __shared__ float tile[64][65];
  const int t = threadIdx.x;
  const int dc = blockIdx.x, h = blockIdx.y, s = blockIdx.z;
  const float* W = (s == 0) ? Wq : (s == 1) ? Wk : Wv;
  unsigned short* T = (s == 0) ? Tq : (s == 1) ? Tk : Tv;
#pragma unroll
  for (int i = 0; i < 4; ++i) {
    int idx = i * 256 + t;
    int d = idx >> 4, kg = idx & 15;
    float4 v = *(const float4*)(W + ((size_t)h * DM + dc * 64 + d) * DKV + kg * 4);
    tile[d][kg * 4 + 0] = v.x; tile[d][kg * 4 + 1] = v.y;
    tile[d][kg * 4 + 2] = v.z; tile[d][kg * 4 + 3] = v.w;
  }
  __syncthreads();
  int k = t >> 2, dg = t & 3;
  union { unsigned short u[8]; int4 v; } o0, o1;
#pragma unroll
  for (int j = 0; j < 8; ++j) o0.u[j] = f2bf(tile[dg * 16 + j][k]);
#pragma unroll
  for (int j = 0; j < 8; ++j) o1.u[j] = f2bf(tile[dg * 16 + 8 + j][k]);
  unsigned short* dst = T + ((size_t)h * DKV + k) * DM + dc * 64 + dg * 16;
  *(int4*)dst = o0.v;
  *(int4*)(dst + 8) = o1.v;
}

// ---------------- mask -> packed bits (bit=1 means VALID) ----------------
__global__ void k_pack(const int* __restrict__ m, uint32_t* __restrict__ out) {
  int wi = blockIdx.x * 256 + threadIdx.x;       // word index, 32 s-positions each
  const int* p = m + (size_t)wi * 32;
  uint32_t bits = 0;
#pragma unroll
  for (int i = 0; i < 8; ++i) {
    int4 v = *(const int4*)(p + i * 4);
    bits |= ((uint32_t)(v.x != 0)) << (i * 4 + 0);
    bits |= ((uint32_t)(v.y != 0)) << (i * 4 + 1);
    bits |= ((uint32_t)(v.z != 0)) << (i * 4 + 2);
    bits |= ((uint32_t)(v.w != 0)) << (i * 4 + 3);
  }
  out[wi] = bits;
}

// ---- GEMM: C = A_fp32[8192x1024] @ BT_bf16[1024x1024]^T + bias (A converted on the fly) ----
// EPI 0: C bf16 [8192][1024] (row, n) ; EPI 1: C bf16 VT[b][h][v][s]
// 128x128 tile, BK=32, 4 waves 2x2. A: reg-staged fp32->bf16 + swizzled ds_write.
// B: global_load_lds w/ source-pre-swizzled XOR (rule #21: linear dest).
template <int EPI>
__global__ __launch_bounds__(256, 2)
void k_gemmF(const float* __restrict__ A, const unsigned short* __restrict__ BT,
             const float* __restrict__ bias, unsigned short* __restrict__ C) {
  __shared__ char As[8192];   // [128][32] bf16, pos p holds source slot p^(row&3)
  __shared__ char Bs[8192];
  const int t = threadIdx.x;
  const int w = t >> 6, lane = t & 63;
  const int g = lane >> 4, r16 = lane & 15;
  const int wm = w >> 1, wn = w & 1;
  const int m0 = blockIdx.y * 128, n0 = blockIdx.x * 128;
  const int arow = t >> 2, ac = t & 3;   // staging coords: row (+0/+64), 8-elem slot

  f32x4 acc[4][4] = {};
  for (int kt = 0; kt < DM / 32; ++kt) {
    // A fp32 -> registers (global reads, no LDS touch; issued before barrier)
    float4 a0[2], a1[2];
#pragma unroll
    for (int i = 0; i < 2; ++i) {
      const float* src = A + (size_t)(m0 + arow + i * 64) * DM + kt * 32 + ac * 8;
      a0[i] = *(const float4*)src;
      a1[i] = *(const float4*)(src + 4);
    }
    __syncthreads();                       // prior-iter LDS readers done
#pragma unroll
    for (int i = 0; i < 2; ++i) {
      int row = arow + i * 64;
      int pos = ac ^ (row & 3);
      // B: 64 rows per call, linear LDS dest + inverse-swizzled source
      gload_lds16(BT + (size_t)(n0 + row) * DM + kt * 32 + pos * 8,
                  Bs + i * 4096 + w * 1024);
      // A: convert + swizzled ds_write_b128
      union { unsigned short u[8]; int4 v; } o;
      o.u[0] = f2bf(a0[i].x); o.u[1] = f2bf(a0[i].y);
      o.u[2] = f2bf(a0[i].z); o.u[3] = f2bf(a0[i].w);
      o.u[4] = f2bf(a1[i].x); o.u[5] = f2bf(a1[i].y);
      o.u[6] = f2bf(a1[i].z); o.u[7] = f2bf(a1[i].w);
      *(int4*)(As + row * 64 + (pos << 4)) = o.v;
    }
    __syncthreads();                       // drains vmcnt + lgkmcnt
    bf16x8 af[4], bfr[4];
#pragma unroll
    for (int m = 0; m < 4; ++m) {
      int row = wm * 64 + m * 16 + r16;
      af[m] = *(const bf16x8*)(As + row * 64 + ((g ^ (row & 3)) << 4));
    }
#pragma unroll
    for (int n = 0; n < 4; ++n) {
      int row = wn * 64 + n * 16 + r16;
      bfr[n] = *(const bf16x8*)(Bs + row * 64 + ((g ^ (row & 3)) << 4));
    }
#pragma unroll
    for (int m = 0; m < 4; ++m)
#pragma unroll
      for (int n = 0; n < 4; ++n)
        acc[m][n] = __builtin_amdgcn_mfma_f32_16x16x32_bf16(af[m], bfr[n], acc[m][n], 0, 0, 0);
  }
#pragma unroll
  for (int m = 0; m < 4; ++m) {
    int rowb = m0 + wm * 64 + m * 16 + 4 * g;     // 4 consecutive rows rowb..rowb+3
#pragma unroll
    for (int n = 0; n < 4; ++n) {
      int col = n0 + wn * 64 + n * 16 + r16;
      float bv = bias[col];
      if (EPI == 0) {
#pragma unroll
        for (int r = 0; r < 4; ++r)
          C[(size_t)(rowb + r) * DM + col] = f2bf(acc[m][n][r] + bv);
      } else {
        int b = rowb >> 10, s = rowb & 1023;
        int h = col >> 6, v = col & 63;
        union { unsigned short u[4]; ushort4 q; } o;
#pragma unroll
        for (int r = 0; r < 4; ++r) o.u[r] = f2bf(acc[m][n][r] + bv);
        *(ushort4*)(C + (((size_t)(b * NH + h) * DKV + v) << 10) + s) = o.q;
      }
    }
  }
}

// ---------------- fused masked attention (swapped-QK^T, lane-local softmax rows) ----
// grid (16 q-tiles, B*H). block 256 = 4 waves; wave owns 16 q-rows (q = q0 + lane&15).
// S^T = mfma(K_frag, Q_frag): q = lane&15, s = f*16+4g+r (regs) -> row softmax is
// in-register tree + 2 shuffles. O^T = mfma(VT_frag, P_frag). P through per-wave LDS
// row q: 4x ds_write_b64 (slot ^ 2*(r16&7)) / 2x ds_read_b128 (chunk ^ (r16&7)).
__global__ __launch_bounds__(256, 2)
void k_attn(const unsigned short* __restrict__ Q, const unsigned short* __restrict__ K,
            const unsigned short* __restrict__ VT, const uint32_t* __restrict__ MP,
            float* __restrict__ O) {
  __shared__ char Ks[8192];   // [64 s][64 d] bf16, chunk^=(row&7)
  __shared__ char Vs[8192];   // [64 v][64 s] bf16, chunk^=(row&7)
  __shared__ char Ps[8192];   // per-wave [16 q][64 s] bf16, slot8^=2*(q&7)
  const int t = threadIdx.x, w = t >> 6, lane = t & 63;
  const int g = lane >> 4, r16 = lane & 15;
  const int qt = blockIdx.x, bh = blockIdx.y;
  const int b = bh >> 4, h = bh & 15;
  const int q0 = qt * 64 + w * 16;
  const int q = q0 + r16;                 // this lane's q row
  const int g4 = g * 4;
  const int x7 = r16 & 7;

  // Q as B-operand fragment (row = lane&15 = q)
  bf16x8 aq[2];
#pragma unroll
  for (int kc = 0; kc < 2; ++kc)
    aq[kc] = *(const bf16x8*)(Q + (size_t)(b * SLEN + q) * DM + h * DKV + kc * 32 + g * 8);

  f32x4 oacc[4] = {};                     // O^T: v = n*16+4g+r (regs), q = r16 (lane)
  float mrun = -1e30f, lrun = 0.f;
  const float SCL = 0.125f * L2E;         // fold 1/sqrt(dk) and log2(e)

  const unsigned short* Kbase = K  + (size_t)b * SLEN * DM + h * DKV;
  const unsigned short* Vbase = VT + (size_t)bh * DKV * SLEN;
  const uint32_t*       Mlane = MP + (size_t)(b * SLEN + q) * 32;
  char* PsW = Ps + w * 2048 + r16 * 128;  // this lane's q-row (write and read)

  for (int st = 0; st < 16; ++st) {
    const int s0 = st * 64;
    // mask words for this lane's q row (independent of LDS; issue early)
    uint32_t mw0 = Mlane[(s0 >> 5) + 0] >> g4;
    uint32_t mw1 = Mlane[(s0 >> 5) + 1] >> g4;
    __syncthreads();
#pragma unroll
    for (int i = 0; i < 2; ++i) {          // 32 rows per call
      int row  = (t >> 3) + i * 32;
      int slot = (t & 7) ^ (row & 7);
      gload_lds16(Kbase + (size_t)(s0 + row) * DM + slot * 8, Ks + i * 4096 + w * 1024);
      gload_lds16(Vbase + (size_t)row * SLEN + s0 + slot * 8, Vs + i * 4096 + w * 1024);
    }
    __syncthreads();

    // S^T = K Q^T : sacc[f][r] = S[q][s0 + f*16 + 4g + r]
    f32x4 sacc[4];
#pragma unroll
    for (int f = 0; f < 4; ++f) {
      sacc[f] = (f32x4){0.f, 0.f, 0.f, 0.f};
#pragma unroll
      for (int kc = 0; kc < 2; ++kc) {
        bf16x8 bk_ = *(const bf16x8*)(Ks + (f * 16 + r16) * 128 + (((kc * 4 + g) ^ x7) << 4));
        sacc[f] = __builtin_amdgcn_mfma_f32_16x16x32_bf16(bk_, aq[kc], sacc[f], 0, 0, 0);
      }
    }

    // mask + scale into log2 domain; in-register row max
#pragma unroll
    for (int f = 0; f < 4; ++f) {
      uint32_t mwf = (f < 2) ? mw0 : mw1;
#pragma unroll
      for (int r = 0; r < 4; ++r) {
        uint32_t bit = (mwf >> (((f & 1) << 4) + r)) & 1u;
        sacc[f][r] = bit ? sacc[f][r] * SCL : -1e30f;
      }
    }
    float tm0 = fmaxf(fmaxf(sacc[0][0], sacc[0][1]), fmaxf(sacc[0][2], sacc[0][3]));
    float tm1 = fmaxf(fmaxf(sacc[1][0], sacc[1][1]), fmaxf(sacc[1][2], sacc[1][3]));
    float tm2 = fmaxf(fmaxf(sacc[2][0], sacc[2][1]), fmaxf(sacc[2][2], sacc[2][3]));
    float tm3 = fmaxf(fmaxf(sacc[3][0], sacc[3][1]), fmaxf(sacc[3][2], sacc[3][3]));
    float mt = fmaxf(fmaxf(tm0, tm1), fmaxf(tm2, tm3));
    mt = fmaxf(mt, __shfl_xor(mt, 16));
    mt = fmaxf(mt, __shfl_xor(mt, 32));

    float mnew = fmaxf(mrun, mt);
    float corr = __builtin_amdgcn_exp2f(mrun - mnew);
#pragma unroll
    for (int f = 0; f < 4; ++f)
#pragma unroll
      for (int r = 0; r < 4; ++r)
        sacc[f][r] = __builtin_amdgcn_exp2f(sacc[f][r] - mnew);
    float ts0 = (sacc[0][0] + sacc[0][1]) + (sacc[0][2] + sacc[0][3]);
    float ts1 = (sacc[1][0] + sacc[1][1]) + (sacc[1][2] + sacc[1][3]);
    float ts2 = (sacc[2][0] + sacc[2][1]) + (sacc[2][2] + sacc[2][3]);
    float ts3 = (sacc[3][0] + sacc[3][1]) + (sacc[3][2] + sacc[3][3]);
    float lt = (ts0 + ts1) + (ts2 + ts3);
    lt += __shfl_xor(lt, 16);
    lt += __shfl_xor(lt, 32);
    lrun = lrun * corr + lt;
    mrun = mnew;
#pragma unroll
    for (int n = 0; n < 4; ++n) oacc[n] *= corr;

    // P pack (cvt_pk) + write: row q=r16, slot8 = ((f<<2)|g) ^ (2*(q&7))
#pragma unroll
    for (int f = 0; f < 4; ++f) {
      uint32_t lo, hi;
      asm("v_cvt_pk_bf16_f32 %0, %1, %2" : "=v"(lo) : "v"(sacc[f][0]), "v"(sacc[f][1]));
      asm("v_cvt_pk_bf16_f32 %0, %1, %2" : "=v"(hi) : "v"(sacc[f][2]), "v"(sacc[f][3]));
      int slot = ((f << 2) | g) ^ (x7 << 1);
      uint2 pk; pk.x = lo; pk.y = hi;
      *(uint2*)(PsW + slot * 8) = pk;
    }
    // P as B-operand fragment: 16B chunk = (kc*4+g) ^ (q&7)
    bf16x8 pa[2];
#pragma unroll
    for (int kc = 0; kc < 2; ++kc)
      pa[kc] = *(const bf16x8*)(PsW + (((kc * 4 + g) ^ x7) << 4));

    // O^T += V^T P^T
#pragma unroll
    for (int n = 0; n < 4; ++n)
#pragma unroll
      for (int kc = 0; kc < 2; ++kc) {
        bf16x8 bv_ = *(const bf16x8*)(Vs + (n * 16 + r16) * 128 + (((kc * 4 + g) ^ x7) << 4));
        oacc[n] = __builtin_amdgcn_mfma_f32_16x16x32_bf16(bv_, pa[kc], oacc[n], 0, 0, 0);
      }
  }

  float inv = (mrun > -5e29f) ? (1.f / lrun) : 0.f;
  float* Orow = O + (size_t)(b * SLEN + q) * (NH * DKV) + h * DKV;
#pragma unroll
  for (int n = 0; n < 4; ++n) {
    float4 o4;
    o4.x = oacc[n][0] * inv; o4.y = oacc[n][1] * inv;
    o4.z = oacc[n][2] * inv; o4.w = oacc[n][3] * inv;
    *(float4*)(Orow + n * 16 + g4) = o4;
  }
}

extern "C" void kernel_launch(void* const* d_in, const int* in_sizes, int n_in,
                              void* d_out, int out_size, void* d_ws, size_t ws_size,
                              hipStream_t stream) {
  const float* dec = (const float*)d_in[0];
  const float* enc = (const float*)d_in[1];
  const int*   msk = (const int*)d_in[2];
  const float* Wq  = (const float*)d_in[3];
  const float* bq  = (const float*)d_in[4];
  const float* Wk  = (const float*)d_in[5];
  const float* bk  = (const float*)d_in[6];
  const float* Wv  = (const float*)d_in[7];
  const float* bv  = (const float*)d_in[8];
  float* out = (float*)d_out;

  // Compact 55 MB workspace (fits ws_size; larger layout corrupted harness state)
  char* ws = (char*)d_ws;
  const size_t MB = 1ull << 20;
  unsigned short* Tq = (unsigned short*)(ws + 0);        // [16][64][1024] bf16, 2 MB
  unsigned short* Tk = (unsigned short*)(ws + 2 * MB);
  unsigned short* Tv = (unsigned short*)(ws + 4 * MB);
  uint32_t*       MP = (uint32_t*)(ws + 6 * MB);         // [8192][32] bits, 1 MB
  unsigned short* Qb = (unsigned short*)(ws + 7 * MB);   // [8192][1024] bf16, 16 MB
  unsigned short* Kb = (unsigned short*)(ws + 23 * MB);  // 16 MB
  unsigned short* VT = (unsigned short*)(ws + 39 * MB);  // [128][64][1024] bf16, 16 MB

  k_wT<<<dim3(16, 16, 3), dim3(256), 0, stream>>>(Wq, Wk, Wv, Tq, Tk, Tv);
  k_pack<<<dim3(1024), dim3(256), 0, stream>>>(msk, MP);
  k_gemmF<0><<<dim3(8, 64), dim3(256), 0, stream>>>(dec, Tq, bq, Qb);
  k_gemmF<0><<<dim3(8, 64), dim3(256), 0, stream>>>(enc, Tk, bk, Kb);
  k_gemmF<1><<<dim3(8, 64), dim3(256), 0, stream>>>(enc, Tv, bv, VT);
  k_attn<<<dim3(16, 128), dim3(256), 0, stream>>>(Qb, Kb, VT, MP, out);
}